// Round 8
// baseline (1073.197 us; speedup 1.0000x reference)
//
#include <hip/hip_runtime.h>
#include <math.h>

#define EPS 1e-5f

__device__ __forceinline__ float gelu_exact(float v) {
    return 0.5f * v * (1.0f + erff(v * 0.70710678118654752f));
}

// ---------- segment boundaries from sorted batch ----------
__global__ void seg_bounds_k(const int* __restrict__ batch, int N, int G, int* __restrict__ seg) {
    int i = blockIdx.x * blockDim.x + threadIdx.x;
    if (i >= N) return;
    int b = batch[i];
    if (i == 0) {
        for (int g = 0; g <= b; ++g) seg[g] = 0;
    } else {
        int pb = batch[i - 1];
        for (int g = pb + 1; g <= b; ++g) seg[g] = i;
    }
    if (i == N - 1) {
        for (int g = b + 1; g <= G; ++g) seg[g] = N;
    }
}

// ---------- CSR build ----------
__global__ void hist_k(const int* __restrict__ ei, int E, int Etot, int* __restrict__ cnt) {
    int e = blockIdx.x * blockDim.x + threadIdx.x;
    if (e >= Etot) return;
    int dst = (e < E) ? ei[E + e] : (e - E);
    atomicAdd(&cnt[dst], 1);
}

__global__ void scan_k(const int* __restrict__ cnt, int N, int* __restrict__ rowptr) {
    __shared__ int ts[1024];
    int t = threadIdx.x;
    int chunk = (N + 1023) / 1024;
    int s0 = t * chunk;
    int e0 = min(s0 + chunk, N);
    int sum = 0;
    for (int i = s0; i < e0; ++i) sum += cnt[i];
    ts[t] = sum;
    __syncthreads();
    for (int off = 1; off < 1024; off <<= 1) {
        int v = (t >= off) ? ts[t - off] : 0;
        __syncthreads();
        ts[t] += v;
        __syncthreads();
    }
    int run = (t > 0) ? ts[t - 1] : 0;
    for (int i = s0; i < e0; ++i) {
        rowptr[i] = run;
        run += cnt[i];
    }
    if (t == 1023) rowptr[N] = ts[1023];
}

__global__ void scatter_k(const int* __restrict__ ei, int E, int Etot,
                          const int* __restrict__ rowptr, int* __restrict__ cur,
                          int* __restrict__ esrc) {
    int e = blockIdx.x * blockDim.x + threadIdx.x;
    if (e >= Etot) return;
    int src, dst;
    if (e < E) { src = ei[e]; dst = ei[E + e]; }
    else       { src = e - E; dst = src; }
    int pos = rowptr[dst] + atomicAdd(&cur[dst], 1);
    esrc[pos] = src;
}

// ---------- fused triple linear v2: 2D register tiling, LDS-staged W ----------
template <int M, int CGN, int RGN, int TM>
__global__ void __launch_bounds__(CGN * RGN) linear3v2_k(
        const float* __restrict__ A,
        const float* __restrict__ W0, const float* __restrict__ b0,
        const float* __restrict__ W1, const float* __restrict__ b1,
        const float* __restrict__ W2, const float* __restrict__ b2,
        float* __restrict__ o0, float* __restrict__ o1, float* __restrict__ o2,
        int nrows) {
    constexpr int K = 128;
    constexpr int BK = 32;
    constexpr int BM = RGN * TM;
    constexpr int NT = CGN * RGN;
    __shared__ float xs[BM * BK];
    __shared__ float ws[3 * BK * M];
    int t = threadIdx.x;
    int row0 = blockIdx.x * BM;
    int cg = t % CGN, rg = t / CGN;
    int c0 = cg * 4;
    int r0 = rg * TM;

    float acc[3][TM][4];
    {
        float4 v0 = *reinterpret_cast<const float4*>(&b0[c0]);
        float4 v1 = *reinterpret_cast<const float4*>(&b1[c0]);
        float4 v2 = *reinterpret_cast<const float4*>(&b2[c0]);
#pragma unroll
        for (int r = 0; r < TM; ++r) {
            acc[0][r][0] = v0.x; acc[0][r][1] = v0.y; acc[0][r][2] = v0.z; acc[0][r][3] = v0.w;
            acc[1][r][0] = v1.x; acc[1][r][1] = v1.y; acc[1][r][2] = v1.z; acc[1][r][3] = v1.w;
            acc[2][r][0] = v2.x; acc[2][r][1] = v2.y; acc[2][r][2] = v2.z; acc[2][r][3] = v2.w;
        }
    }

    for (int k0 = 0; k0 < K; k0 += BK) {
        if (k0) __syncthreads();
        // stage x tile (swizzled 16B slots)
        for (int idx = t; idx < BM * 8; idx += NT) {
            int r = idx >> 3, j = idx & 7;
            int grow = row0 + r;
            float4 v = make_float4(0.f, 0.f, 0.f, 0.f);
            if (grow < nrows) v = *reinterpret_cast<const float4*>(&A[(long)grow * K + k0 + j * 4]);
            int swz = (r ^ (r >> 3)) & 7;
            *reinterpret_cast<float4*>(&xs[r * BK + ((j ^ swz) << 2)]) = v;
        }
        // stage 3 W tiles (linear)
        for (int idx = t; idx < BK * (M / 4); idx += NT) {
            int kk = idx / (M / 4), c4 = idx % (M / 4);
            long goff = (long)(k0 + kk) * M + c4 * 4;
            int loff = kk * M + c4 * 4;
            *reinterpret_cast<float4*>(&ws[loff]) =
                *reinterpret_cast<const float4*>(&W0[goff]);
            *reinterpret_cast<float4*>(&ws[BK * M + loff]) =
                *reinterpret_cast<const float4*>(&W1[goff]);
            *reinterpret_cast<float4*>(&ws[2 * BK * M + loff]) =
                *reinterpret_cast<const float4*>(&W2[goff]);
        }
        __syncthreads();

#pragma unroll
        for (int k4 = 0; k4 < BK; k4 += 4) {
            float4 wv[3][4];
#pragma unroll
            for (int m = 0; m < 3; ++m)
#pragma unroll
                for (int kk = 0; kk < 4; ++kk)
                    wv[m][kk] = *reinterpret_cast<const float4*>(
                        &ws[m * BK * M + (k4 + kk) * M + c0]);
#pragma unroll
            for (int r = 0; r < TM; ++r) {
                int rr = r0 + r;
                int swz = (rr ^ (rr >> 3)) & 7;
                float4 xv = *reinterpret_cast<const float4*>(
                    &xs[rr * BK + (((k4 >> 2) ^ swz) << 2)]);
#pragma unroll
                for (int m = 0; m < 3; ++m) {
                    acc[m][r][0] += xv.x * wv[m][0].x + xv.y * wv[m][1].x +
                                    xv.z * wv[m][2].x + xv.w * wv[m][3].x;
                    acc[m][r][1] += xv.x * wv[m][0].y + xv.y * wv[m][1].y +
                                    xv.z * wv[m][2].y + xv.w * wv[m][3].y;
                    acc[m][r][2] += xv.x * wv[m][0].z + xv.y * wv[m][1].z +
                                    xv.z * wv[m][2].z + xv.w * wv[m][3].z;
                    acc[m][r][3] += xv.x * wv[m][0].w + xv.y * wv[m][1].w +
                                    xv.z * wv[m][2].w + xv.w * wv[m][3].w;
                }
            }
        }
    }

#pragma unroll
    for (int r = 0; r < TM; ++r) {
        int grow = row0 + r0 + r;
        if (grow < nrows) {
            long o = (long)grow * M + c0;
            *reinterpret_cast<float4*>(&o0[o]) =
                make_float4(acc[0][r][0], acc[0][r][1], acc[0][r][2], acc[0][r][3]);
            *reinterpret_cast<float4*>(&o1[o]) =
                make_float4(acc[1][r][0], acc[1][r][1], acc[1][r][2], acc[1][r][3]);
            *reinterpret_cast<float4*>(&o2[o]) =
                make_float4(acc[2][r][0], acc[2][r][1], acc[2][r][2], acc[2][r][3]);
        }
    }
}

// ---------- fused GAT layer 1: batch-4 online softmax (F=128, 4 heads) ----------
__global__ void __launch_bounds__(256) gat1_k(
        const float* __restrict__ xl, const float* __restrict__ xr,
        const float* __restrict__ att, const int* __restrict__ rowptr,
        const int* __restrict__ esrc, float* __restrict__ outp, int N) {
    int node = blockIdx.x * 2 + (threadIdx.x >> 7);
    if (node >= N) return;
    int f = threadIdx.x & 127;
    float xrf = xr[(long)node * 128 + f];
    float af = att[f];
    int s = rowptr[node], e = rowptr[node + 1];
    float m = -INFINITY, den = 0.f, acc = 0.f;
    int i = s;
    for (; i + 4 <= e; i += 4) {
        int s0 = esrc[i], s1 = esrc[i + 1], s2 = esrc[i + 2], s3 = esrc[i + 3];
        float x0 = xl[(long)s0 * 128 + f];
        float x1 = xl[(long)s1 * 128 + f];
        float x2 = xl[(long)s2 * 128 + f];
        float x3 = xl[(long)s3 * 128 + f];
        float v0 = x0 + xrf; v0 = ((v0 > 0.f) ? v0 : 0.2f * v0) * af;
        float v1 = x1 + xrf; v1 = ((v1 > 0.f) ? v1 : 0.2f * v1) * af;
        float v2 = x2 + xrf; v2 = ((v2 > 0.f) ? v2 : 0.2f * v2) * af;
        float v3 = x3 + xrf; v3 = ((v3 > 0.f) ? v3 : 0.2f * v3) * af;
#pragma unroll
        for (int off = 16; off > 0; off >>= 1) {
            v0 += __shfl_xor(v0, off, 32);
            v1 += __shfl_xor(v1, off, 32);
            v2 += __shfl_xor(v2, off, 32);
            v3 += __shfl_xor(v3, off, 32);
        }
        float vm = fmaxf(fmaxf(v0, v1), fmaxf(v2, v3));
        float nm = fmaxf(m, vm);
        float sc = __expf(m - nm);
        float p0 = __expf(v0 - nm), p1 = __expf(v1 - nm);
        float p2 = __expf(v2 - nm), p3 = __expf(v3 - nm);
        den = den * sc + ((p0 + p1) + (p2 + p3));
        acc = acc * sc + ((p0 * x0 + p1 * x1) + (p2 * x2 + p3 * x3));
        m = nm;
    }
    for (; i < e; ++i) {
        int srcn = esrc[i];
        float xlv = xl[(long)srcn * 128 + f];
        float v = xlv + xrf;
        v = ((v > 0.f) ? v : 0.2f * v) * af;
#pragma unroll
        for (int off = 16; off > 0; off >>= 1) v += __shfl_xor(v, off, 32);
        float nm = fmaxf(m, v);
        float sc = __expf(m - nm);
        float p  = __expf(v - nm);
        den = den * sc + p;
        acc = acc * sc + p * xlv;
        m = nm;
    }
    outp[(long)node * 128 + f] = acc / den;
}

// ---------- fused GAT layer 2: batch-4 online softmax (F=32, 1 head) ----------
__global__ void __launch_bounds__(256) gat2_k(
        const float* __restrict__ xl, const float* __restrict__ xr,
        const float* __restrict__ att, const int* __restrict__ rowptr,
        const int* __restrict__ esrc, float* __restrict__ outp, int N) {
    int node = blockIdx.x * 8 + (threadIdx.x >> 5);
    if (node >= N) return;
    int f = threadIdx.x & 31;
    float xrf = xr[(long)node * 32 + f];
    float af = att[f];
    int s = rowptr[node], e = rowptr[node + 1];
    float m = -INFINITY, den = 0.f, acc = 0.f;
    int i = s;
    for (; i + 4 <= e; i += 4) {
        int s0 = esrc[i], s1 = esrc[i + 1], s2 = esrc[i + 2], s3 = esrc[i + 3];
        float x0 = xl[(long)s0 * 32 + f];
        float x1 = xl[(long)s1 * 32 + f];
        float x2 = xl[(long)s2 * 32 + f];
        float x3 = xl[(long)s3 * 32 + f];
        float v0 = x0 + xrf; v0 = ((v0 > 0.f) ? v0 : 0.2f * v0) * af;
        float v1 = x1 + xrf; v1 = ((v1 > 0.f) ? v1 : 0.2f * v1) * af;
        float v2 = x2 + xrf; v2 = ((v2 > 0.f) ? v2 : 0.2f * v2) * af;
        float v3 = x3 + xrf; v3 = ((v3 > 0.f) ? v3 : 0.2f * v3) * af;
#pragma unroll
        for (int off = 16; off > 0; off >>= 1) {
            v0 += __shfl_xor(v0, off, 32);
            v1 += __shfl_xor(v1, off, 32);
            v2 += __shfl_xor(v2, off, 32);
            v3 += __shfl_xor(v3, off, 32);
        }
        float vm = fmaxf(fmaxf(v0, v1), fmaxf(v2, v3));
        float nm = fmaxf(m, vm);
        float sc = __expf(m - nm);
        float p0 = __expf(v0 - nm), p1 = __expf(v1 - nm);
        float p2 = __expf(v2 - nm), p3 = __expf(v3 - nm);
        den = den * sc + ((p0 + p1) + (p2 + p3));
        acc = acc * sc + ((p0 * x0 + p1 * x1) + (p2 * x2 + p3 * x3));
        m = nm;
    }
    for (; i < e; ++i) {
        int srcn = esrc[i];
        float xlv = xl[(long)srcn * 32 + f];
        float v = xlv + xrf;
        v = ((v > 0.f) ? v : 0.2f * v) * af;
#pragma unroll
        for (int off = 16; off > 0; off >>= 1) v += __shfl_xor(v, off, 32);
        float nm = fmaxf(m, v);
        float sc = __expf(m - nm);
        float p  = __expf(v - nm);
        den = den * sc + p;
        acc = acc * sc + p * xlv;
        m = nm;
    }
    outp[(long)node * 32 + f] = acc / den;
}

// ---------- graph norm stats: 2D block (F x NW), LDS reduce ----------
template <int F, int NW>
__global__ void gn_stats_k(const float* __restrict__ x, const float* __restrict__ bias,
                           const float* __restrict__ ms, const int* __restrict__ seg,
                           float* __restrict__ meanp, float* __restrict__ istdp) {
    __shared__ float s1s[NW][F];
    __shared__ float s2s[NW][F];
    int g = blockIdx.x;
    int f = threadIdx.x % F, j = threadIdx.x / F;
    int s = seg[g], e = seg[g + 1];
    int count = e - s;
    float bv = bias[f];
    float s1 = 0.f, s2 = 0.f;
    for (int n = s + j; n < e; n += NW) {
        float v = x[(long)n * F + f] + bv;
        s1 += v;
        s2 += v * v;
    }
    s1s[j][f] = s1;
    s2s[j][f] = s2;
    __syncthreads();
    if (j == 0) {
#pragma unroll
        for (int jj = 1; jj < NW; ++jj) { s1 += s1s[jj][f]; s2 += s2s[jj][f]; }
        float cnt = (float)max(count, 1);
        float mean = s1 / cnt;
        float mms = mean * ms[f];
        float var = s2 / cnt - 2.f * mms * mean + mms * mms;
        meanp[(long)g * F + f] = mean;
        istdp[(long)g * F + f] = 1.0f / sqrtf(var + EPS);
    }
}

// ---------- graph norm apply + residual + exact GELU (float4) ----------
template <int F>
__global__ void gn_apply_k(const float* __restrict__ x, const float* __restrict__ bias,
                           const int* __restrict__ batch, const float* __restrict__ meanp,
                           const float* __restrict__ istdp, const float* __restrict__ w,
                           const float* __restrict__ b, const float* __restrict__ ms,
                           const float* __restrict__ res, float* __restrict__ h, int N) {
    constexpr int F4 = F / 4;
    long i = (long)blockIdx.x * blockDim.x + threadIdx.x;
    if (i >= (long)N * F4) return;
    int n = (int)(i / F4), f4 = (int)(i % F4);
    int g = batch[n];
    long base = (long)n * F + f4 * 4;
    long gbase = (long)g * F + f4 * 4;
    float4 xv = *reinterpret_cast<const float4*>(&x[base]);
    float4 rv = *reinterpret_cast<const float4*>(&res[base]);
    float4 mv = *reinterpret_cast<const float4*>(&meanp[gbase]);
    float4 iv = *reinterpret_cast<const float4*>(&istdp[gbase]);
    float4 bv = *reinterpret_cast<const float4*>(&bias[f4 * 4]);
    float4 wv = *reinterpret_cast<const float4*>(&w[f4 * 4]);
    float4 bb = *reinterpret_cast<const float4*>(&b[f4 * 4]);
    float4 mw = *reinterpret_cast<const float4*>(&ms[f4 * 4]);
    float4 o;
    o.x = gelu_exact(wv.x * ((xv.x + bv.x) - mv.x * mw.x) * iv.x + bb.x + rv.x);
    o.y = gelu_exact(wv.y * ((xv.y + bv.y) - mv.y * mw.y) * iv.y + bb.y + rv.y);
    o.z = gelu_exact(wv.z * ((xv.z + bv.z) - mv.z * mw.z) * iv.z + bb.z + rv.z);
    o.w = gelu_exact(wv.w * ((xv.w + bv.w) - mv.w * mw.w) * iv.w + bb.w + rv.w);
    *reinterpret_cast<float4*>(&h[base]) = o;
}

// ---------- pooling + ego gate + MLP head ----------
__global__ void pool_head_k(const float* __restrict__ h2, const int* __restrict__ seg,
                            const float* __restrict__ Weg, const float* __restrict__ beg,
                            const float* __restrict__ Wf1, const float* __restrict__ bf1,
                            const float* __restrict__ Wf2, const float* __restrict__ bf2,
                            float* __restrict__ outp) {
    int g = blockIdx.x, t = threadIdx.x;
    int s = seg[g], epos = seg[g + 1];
    int count = epos - s;
    __shared__ float ssum[8][32];
    __shared__ float smax[8][32];
    __shared__ float xfinal[96];
    __shared__ float emb[32];
    int f = t % 32, j = t / 32;
    float sum = 0.f, mx = -INFINITY;
    for (int n = s + j; n < epos; n += 8) {
        float v = h2[(long)n * 32 + f];
        sum += v;
        mx = fmaxf(mx, v);
    }
    ssum[j][f] = sum;
    smax[j][f] = mx;
    __syncthreads();
    if (t < 32) {
        float acs = 0.f, acm = -INFINITY;
        for (int jj = 0; jj < 8; ++jj) { acs += ssum[jj][t]; acm = fmaxf(acm, smax[jj][t]); }
        float mean = acs / (float)max(count, 1);
        float mxv = (count > 0) ? acm : 0.0f;
        xfinal[t] = mean;
        smax[0][t] = mxv;
    }
    __syncthreads();
    if (t < 64) {
        float acc = beg[t];
        for (int k = 0; k < 32; ++k) acc += xfinal[k] * Weg[k * 64 + t];
        float gate = 1.0f / (1.0f + expf(-acc));
        float val = (t < 32) ? xfinal[t] : smax[0][t - 32];
        xfinal[32 + t] = gate * val;
    }
    __syncthreads();
    if (t < 32) {
        float acc = bf1[t];
        for (int k = 0; k < 96; ++k) acc += xfinal[k] * Wf1[k * 32 + t];
        emb[t] = gelu_exact(acc);
    }
    __syncthreads();
    if (t < 32) {
        float v = emb[t] * Wf2[t];
#pragma unroll
        for (int off = 16; off > 0; off >>= 1) v += __shfl_xor(v, off, 32);
        if (t == 0) outp[g] = v + bf2[0];
    }
}

// ---------- launcher ----------
extern "C" void kernel_launch(void* const* d_in, const int* in_sizes, int n_in, void* d_out,
                              int out_size, void* d_ws, size_t ws_size, hipStream_t stream) {
    const float* x      = (const float*)d_in[0];
    const int*   ei     = (const int*)d_in[1];
    const int*   batch  = (const int*)d_in[2];
    const float* Wl1    = (const float*)d_in[3];
    const float* bl1    = (const float*)d_in[4];
    const float* Wr1    = (const float*)d_in[5];
    const float* br1    = (const float*)d_in[6];
    const float* att1   = (const float*)d_in[7];
    const float* bias1  = (const float*)d_in[8];
    const float* gn1_w  = (const float*)d_in[9];
    const float* gn1_b  = (const float*)d_in[10];
    const float* gn1_ms = (const float*)d_in[11];
    const float* Wl2    = (const float*)d_in[12];
    const float* bl2    = (const float*)d_in[13];
    const float* Wr2    = (const float*)d_in[14];
    const float* br2    = (const float*)d_in[15];
    const float* att2   = (const float*)d_in[16];
    const float* bias2  = (const float*)d_in[17];
    const float* gn2_w  = (const float*)d_in[18];
    const float* gn2_b  = (const float*)d_in[19];
    const float* gn2_ms = (const float*)d_in[20];
    const float* Wp1    = (const float*)d_in[21];
    const float* bp1    = (const float*)d_in[22];
    const float* Wp2    = (const float*)d_in[23];
    const float* bp2    = (const float*)d_in[24];
    const float* Weg    = (const float*)d_in[25];
    const float* beg    = (const float*)d_in[26];
    const float* Wf1    = (const float*)d_in[27];
    const float* bf1    = (const float*)d_in[28];
    const float* Wf2    = (const float*)d_in[29];
    const float* bf2    = (const float*)d_in[30];
    float* outp = (float*)d_out;

    const int N = in_sizes[2];
    const int E = in_sizes[1] / 2;
    const int Etot = E + N;
    const int G = out_size;
    constexpr int HC = 128, C = 32;

    char* ws = (char*)d_ws;
    size_t off = 0;
    auto alloc = [&](size_t bytes) -> void* {
        void* p = ws + off;
        off += (bytes + 255) & ~(size_t)255;
        return p;
    };
    int*   seg    = (int*)alloc((size_t)(G + 1) * 4);
    int*   cnt    = (int*)alloc((size_t)N * 4);
    int*   cur    = (int*)alloc((size_t)N * 4);
    int*   rowptr = (int*)alloc((size_t)(N + 1) * 4);
    int*   esrc   = (int*)alloc((size_t)Etot * 4);
    float* xl1    = (float*)alloc((size_t)N * HC * 4);
    float* xr1    = (float*)alloc((size_t)N * HC * 4);
    float* res1   = (float*)alloc((size_t)N * HC * 4);
    float* out1   = (float*)alloc((size_t)N * HC * 4);
    float* mean1  = (float*)alloc((size_t)G * HC * 4);
    float* istd1  = (float*)alloc((size_t)G * HC * 4);
    float* xl2    = (float*)alloc((size_t)N * C * 4);
    float* xr2    = (float*)alloc((size_t)N * C * 4);
    float* res2   = (float*)alloc((size_t)N * C * 4);
    float* out2   = (float*)alloc((size_t)N * C * 4);
    float* h2     = (float*)alloc((size_t)N * C * 4);
    float* mean2  = (float*)alloc((size_t)G * C * 4);
    float* istd2  = (float*)alloc((size_t)G * C * 4);
    float* h1     = xl1;  // alias: xl1 dead after gat1_k
    (void)ws_size; (void)n_in;

    // init + CSR build
    seg_bounds_k<<<(N + 255) / 256, 256, 0, stream>>>(batch, N, G, seg);
    hipMemsetAsync(cnt, 0, (size_t)N * 4, stream);
    hipMemsetAsync(cur, 0, (size_t)N * 4, stream);
    hist_k<<<(Etot + 255) / 256, 256, 0, stream>>>(ei, E, Etot, cnt);
    scan_k<<<1, 1024, 0, stream>>>(cnt, N, rowptr);
    scatter_k<<<(Etot + 255) / 256, 256, 0, stream>>>(ei, E, Etot, rowptr, cur, esrc);

    // ---- layer 1 ----
    linear3v2_k<128, 32, 8, 8><<<(N + 63) / 64, 256, 0, stream>>>(
        x, Wl1, bl1, Wr1, br1, Wp1, bp1, xl1, xr1, res1, N);
    gat1_k<<<(N + 1) / 2, 256, 0, stream>>>(xl1, xr1, att1, rowptr, esrc, out1, N);
    gn_stats_k<128, 4><<<G, 512, 0, stream>>>(out1, bias1, gn1_ms, seg, mean1, istd1);
    gn_apply_k<128><<<(int)(((long)N * 32 + 255) / 256), 256, 0, stream>>>(
        out1, bias1, batch, mean1, istd1, gn1_w, gn1_b, gn1_ms, res1, h1, N);

    // ---- layer 2 ----
    linear3v2_k<32, 8, 16, 8><<<(N + 127) / 128, 128, 0, stream>>>(
        h1, Wl2, bl2, Wr2, br2, Wp2, bp2, xl2, xr2, res2, N);
    gat2_k<<<(N + 7) / 8, 256, 0, stream>>>(xl2, xr2, att2, rowptr, esrc, out2, N);
    gn_stats_k<32, 16><<<G, 512, 0, stream>>>(out2, bias2, gn2_ms, seg, mean2, istd2);
    gn_apply_k<32><<<(int)(((long)N * 8 + 255) / 256), 256, 0, stream>>>(
        out2, bias2, batch, mean2, istd2, gn2_w, gn2_b, gn2_ms, res2, h2, N);

    // ---- pooling + gate + head ----
    pool_head_k<<<G, 256, 0, stream>>>(h2, seg, Weg, beg, Wf1, bf1, Wf2, bf2, outp);
}

// Round 16
// 570.566 us; speedup vs baseline: 1.8809x; 1.8809x over previous
//
#include <hip/hip_runtime.h>
#include <math.h>

#define EPS 1e-5f

__device__ __forceinline__ float gelu_exact(float v) {
    return 0.5f * v * (1.0f + erff(v * 0.70710678118654752f));
}

// ---------- segment boundaries from sorted batch ----------
__global__ void seg_bounds_k(const int* __restrict__ batch, int N, int G, int* __restrict__ seg) {
    int i = blockIdx.x * blockDim.x + threadIdx.x;
    if (i >= N) return;
    int b = batch[i];
    if (i == 0) {
        for (int g = 0; g <= b; ++g) seg[g] = 0;
    } else {
        int pb = batch[i - 1];
        for (int g = pb + 1; g <= b; ++g) seg[g] = i;
    }
    if (i == N - 1) {
        for (int g = b + 1; g <= G; ++g) seg[g] = N;
    }
}

// ---------- CSR build ----------
__global__ void hist_k(const int* __restrict__ ei, int E, int Etot, int* __restrict__ cnt) {
    int e = blockIdx.x * blockDim.x + threadIdx.x;
    if (e >= Etot) return;
    int dst = (e < E) ? ei[E + e] : (e - E);
    atomicAdd(&cnt[dst], 1);
}

__global__ void scan_k(const int* __restrict__ cnt, int N, int* __restrict__ rowptr) {
    __shared__ int ts[1024];
    int t = threadIdx.x;
    int chunk = (N + 1023) / 1024;
    int s0 = t * chunk;
    int e0 = min(s0 + chunk, N);
    int sum = 0;
    for (int i = s0; i < e0; ++i) sum += cnt[i];
    ts[t] = sum;
    __syncthreads();
    for (int off = 1; off < 1024; off <<= 1) {
        int v = (t >= off) ? ts[t - off] : 0;
        __syncthreads();
        ts[t] += v;
        __syncthreads();
    }
    int run = (t > 0) ? ts[t - 1] : 0;
    for (int i = s0; i < e0; ++i) {
        rowptr[i] = run;
        run += cnt[i];
    }
    if (t == 1023) rowptr[N] = ts[1023];
}

__global__ void scatter_k(const int* __restrict__ ei, int E, int Etot,
                          const int* __restrict__ rowptr, int* __restrict__ cur,
                          int* __restrict__ esrc) {
    int e = blockIdx.x * blockDim.x + threadIdx.x;
    if (e >= Etot) return;
    int src, dst;
    if (e < E) { src = ei[e]; dst = ei[E + e]; }
    else       { src = e - E; dst = src; }
    int pos = rowptr[dst] + atomicAdd(&cur[dst], 1);
    esrc[pos] = src;
}

// ---------- fused triple linear v3: register-safe 2D tiling ----------
// TM=4 rows/thread, m-outer inner loop (one matrix's weights live at a time),
// k4 loop only 2x unrolled to prevent LDS-read hoisting / liveness explosion.
// VGPR budget: acc 48 + xv 16 + wv 16 + addr ~= 110-150 (no spill; R8 had 256+spill).
template <int M, int CGN, int RGN, int TM>
__global__ void __launch_bounds__(CGN * RGN) linear3v2_k(
        const float* __restrict__ A,
        const float* __restrict__ W0, const float* __restrict__ b0,
        const float* __restrict__ W1, const float* __restrict__ b1,
        const float* __restrict__ W2, const float* __restrict__ b2,
        float* __restrict__ o0, float* __restrict__ o1, float* __restrict__ o2,
        int nrows) {
    constexpr int K = 128;
    constexpr int BK = 32;
    constexpr int BM = RGN * TM;
    constexpr int NT = CGN * RGN;
    __shared__ float xs[BM * BK];
    __shared__ float ws[3 * BK * M];
    int t = threadIdx.x;
    int row0 = blockIdx.x * BM;
    int cg = t % CGN, rg = t / CGN;
    int c0 = cg * 4;
    int r0 = rg * TM;

    float acc[3][TM][4];
    {
        float4 v0 = *reinterpret_cast<const float4*>(&b0[c0]);
        float4 v1 = *reinterpret_cast<const float4*>(&b1[c0]);
        float4 v2 = *reinterpret_cast<const float4*>(&b2[c0]);
#pragma unroll
        for (int r = 0; r < TM; ++r) {
            acc[0][r][0] = v0.x; acc[0][r][1] = v0.y; acc[0][r][2] = v0.z; acc[0][r][3] = v0.w;
            acc[1][r][0] = v1.x; acc[1][r][1] = v1.y; acc[1][r][2] = v1.z; acc[1][r][3] = v1.w;
            acc[2][r][0] = v2.x; acc[2][r][1] = v2.y; acc[2][r][2] = v2.z; acc[2][r][3] = v2.w;
        }
    }

    for (int k0 = 0; k0 < K; k0 += BK) {
        if (k0) __syncthreads();
        // stage x tile (swizzled 16B slots within each 128B row)
        for (int idx = t; idx < BM * 8; idx += NT) {
            int r = idx >> 3, j = idx & 7;
            int grow = row0 + r;
            float4 v = make_float4(0.f, 0.f, 0.f, 0.f);
            if (grow < nrows) v = *reinterpret_cast<const float4*>(&A[(long)grow * K + k0 + j * 4]);
            int swz = (r ^ (r >> 3)) & 7;
            *reinterpret_cast<float4*>(&xs[r * BK + ((j ^ swz) << 2)]) = v;
        }
        // stage 3 W tiles (linear)
        for (int idx = t; idx < BK * (M / 4); idx += NT) {
            int kk = idx / (M / 4), c4 = idx % (M / 4);
            long goff = (long)(k0 + kk) * M + c4 * 4;
            int loff = kk * M + c4 * 4;
            *reinterpret_cast<float4*>(&ws[loff]) =
                *reinterpret_cast<const float4*>(&W0[goff]);
            *reinterpret_cast<float4*>(&ws[BK * M + loff]) =
                *reinterpret_cast<const float4*>(&W1[goff]);
            *reinterpret_cast<float4*>(&ws[2 * BK * M + loff]) =
                *reinterpret_cast<const float4*>(&W2[goff]);
        }
        __syncthreads();

#pragma unroll 2
        for (int k4 = 0; k4 < BK; k4 += 4) {
            float4 xv[TM];
#pragma unroll
            for (int r = 0; r < TM; ++r) {
                int rr = r0 + r;
                int swz = (rr ^ (rr >> 3)) & 7;
                xv[r] = *reinterpret_cast<const float4*>(
                    &xs[rr * BK + (((k4 >> 2) ^ swz) << 2)]);
            }
#pragma unroll
            for (int m = 0; m < 3; ++m) {
                const float* wsm = &ws[m * BK * M + k4 * M + c0];
                float4 w0 = *reinterpret_cast<const float4*>(&wsm[0]);
                float4 w1 = *reinterpret_cast<const float4*>(&wsm[M]);
                float4 w2 = *reinterpret_cast<const float4*>(&wsm[2 * M]);
                float4 w3 = *reinterpret_cast<const float4*>(&wsm[3 * M]);
#pragma unroll
                for (int r = 0; r < TM; ++r) {
                    acc[m][r][0] += xv[r].x * w0.x + xv[r].y * w1.x +
                                    xv[r].z * w2.x + xv[r].w * w3.x;
                    acc[m][r][1] += xv[r].x * w0.y + xv[r].y * w1.y +
                                    xv[r].z * w2.y + xv[r].w * w3.y;
                    acc[m][r][2] += xv[r].x * w0.z + xv[r].y * w1.z +
                                    xv[r].z * w2.z + xv[r].w * w3.z;
                    acc[m][r][3] += xv[r].x * w0.w + xv[r].y * w1.w +
                                    xv[r].z * w2.w + xv[r].w * w3.w;
                }
            }
        }
    }

#pragma unroll
    for (int r = 0; r < TM; ++r) {
        int grow = row0 + r0 + r;
        if (grow < nrows) {
            long o = (long)grow * M + c0;
            *reinterpret_cast<float4*>(&o0[o]) =
                make_float4(acc[0][r][0], acc[0][r][1], acc[0][r][2], acc[0][r][3]);
            *reinterpret_cast<float4*>(&o1[o]) =
                make_float4(acc[1][r][0], acc[1][r][1], acc[1][r][2], acc[1][r][3]);
            *reinterpret_cast<float4*>(&o2[o]) =
                make_float4(acc[2][r][0], acc[2][r][1], acc[2][r][2], acc[2][r][3]);
        }
    }
}

// ---------- fused GAT layer 1: batch-4 online softmax (F=128, 4 heads) ----------
__global__ void __launch_bounds__(256) gat1_k(
        const float* __restrict__ xl, const float* __restrict__ xr,
        const float* __restrict__ att, const int* __restrict__ rowptr,
        const int* __restrict__ esrc, float* __restrict__ outp, int N) {
    int node = blockIdx.x * 2 + (threadIdx.x >> 7);
    if (node >= N) return;
    int f = threadIdx.x & 127;
    float xrf = xr[(long)node * 128 + f];
    float af = att[f];
    int s = rowptr[node], e = rowptr[node + 1];
    float m = -INFINITY, den = 0.f, acc = 0.f;
    int i = s;
    for (; i + 4 <= e; i += 4) {
        int s0 = esrc[i], s1 = esrc[i + 1], s2 = esrc[i + 2], s3 = esrc[i + 3];
        float x0 = xl[(long)s0 * 128 + f];
        float x1 = xl[(long)s1 * 128 + f];
        float x2 = xl[(long)s2 * 128 + f];
        float x3 = xl[(long)s3 * 128 + f];
        float v0 = x0 + xrf; v0 = ((v0 > 0.f) ? v0 : 0.2f * v0) * af;
        float v1 = x1 + xrf; v1 = ((v1 > 0.f) ? v1 : 0.2f * v1) * af;
        float v2 = x2 + xrf; v2 = ((v2 > 0.f) ? v2 : 0.2f * v2) * af;
        float v3 = x3 + xrf; v3 = ((v3 > 0.f) ? v3 : 0.2f * v3) * af;
#pragma unroll
        for (int off = 16; off > 0; off >>= 1) {
            v0 += __shfl_xor(v0, off, 32);
            v1 += __shfl_xor(v1, off, 32);
            v2 += __shfl_xor(v2, off, 32);
            v3 += __shfl_xor(v3, off, 32);
        }
        float vm = fmaxf(fmaxf(v0, v1), fmaxf(v2, v3));
        float nm = fmaxf(m, vm);
        float sc = __expf(m - nm);
        float p0 = __expf(v0 - nm), p1 = __expf(v1 - nm);
        float p2 = __expf(v2 - nm), p3 = __expf(v3 - nm);
        den = den * sc + ((p0 + p1) + (p2 + p3));
        acc = acc * sc + ((p0 * x0 + p1 * x1) + (p2 * x2 + p3 * x3));
        m = nm;
    }
    for (; i < e; ++i) {
        int srcn = esrc[i];
        float xlv = xl[(long)srcn * 128 + f];
        float v = xlv + xrf;
        v = ((v > 0.f) ? v : 0.2f * v) * af;
#pragma unroll
        for (int off = 16; off > 0; off >>= 1) v += __shfl_xor(v, off, 32);
        float nm = fmaxf(m, v);
        float sc = __expf(m - nm);
        float p  = __expf(v - nm);
        den = den * sc + p;
        acc = acc * sc + p * xlv;
        m = nm;
    }
    outp[(long)node * 128 + f] = acc / den;
}

// ---------- fused GAT layer 2: batch-4 online softmax (F=32, 1 head) ----------
__global__ void __launch_bounds__(256) gat2_k(
        const float* __restrict__ xl, const float* __restrict__ xr,
        const float* __restrict__ att, const int* __restrict__ rowptr,
        const int* __restrict__ esrc, float* __restrict__ outp, int N) {
    int node = blockIdx.x * 8 + (threadIdx.x >> 5);
    if (node >= N) return;
    int f = threadIdx.x & 31;
    float xrf = xr[(long)node * 32 + f];
    float af = att[f];
    int s = rowptr[node], e = rowptr[node + 1];
    float m = -INFINITY, den = 0.f, acc = 0.f;
    int i = s;
    for (; i + 4 <= e; i += 4) {
        int s0 = esrc[i], s1 = esrc[i + 1], s2 = esrc[i + 2], s3 = esrc[i + 3];
        float x0 = xl[(long)s0 * 32 + f];
        float x1 = xl[(long)s1 * 32 + f];
        float x2 = xl[(long)s2 * 32 + f];
        float x3 = xl[(long)s3 * 32 + f];
        float v0 = x0 + xrf; v0 = ((v0 > 0.f) ? v0 : 0.2f * v0) * af;
        float v1 = x1 + xrf; v1 = ((v1 > 0.f) ? v1 : 0.2f * v1) * af;
        float v2 = x2 + xrf; v2 = ((v2 > 0.f) ? v2 : 0.2f * v2) * af;
        float v3 = x3 + xrf; v3 = ((v3 > 0.f) ? v3 : 0.2f * v3) * af;
#pragma unroll
        for (int off = 16; off > 0; off >>= 1) {
            v0 += __shfl_xor(v0, off, 32);
            v1 += __shfl_xor(v1, off, 32);
            v2 += __shfl_xor(v2, off, 32);
            v3 += __shfl_xor(v3, off, 32);
        }
        float vm = fmaxf(fmaxf(v0, v1), fmaxf(v2, v3));
        float nm = fmaxf(m, vm);
        float sc = __expf(m - nm);
        float p0 = __expf(v0 - nm), p1 = __expf(v1 - nm);
        float p2 = __expf(v2 - nm), p3 = __expf(v3 - nm);
        den = den * sc + ((p0 + p1) + (p2 + p3));
        acc = acc * sc + ((p0 * x0 + p1 * x1) + (p2 * x2 + p3 * x3));
        m = nm;
    }
    for (; i < e; ++i) {
        int srcn = esrc[i];
        float xlv = xl[(long)srcn * 32 + f];
        float v = xlv + xrf;
        v = ((v > 0.f) ? v : 0.2f * v) * af;
#pragma unroll
        for (int off = 16; off > 0; off >>= 1) v += __shfl_xor(v, off, 32);
        float nm = fmaxf(m, v);
        float sc = __expf(m - nm);
        float p  = __expf(v - nm);
        den = den * sc + p;
        acc = acc * sc + p * xlv;
        m = nm;
    }
    outp[(long)node * 32 + f] = acc / den;
}

// ---------- graph norm stats: 2D block (F x NW), LDS reduce ----------
template <int F, int NW>
__global__ void gn_stats_k(const float* __restrict__ x, const float* __restrict__ bias,
                           const float* __restrict__ ms, const int* __restrict__ seg,
                           float* __restrict__ meanp, float* __restrict__ istdp) {
    __shared__ float s1s[NW][F];
    __shared__ float s2s[NW][F];
    int g = blockIdx.x;
    int f = threadIdx.x % F, j = threadIdx.x / F;
    int s = seg[g], e = seg[g + 1];
    int count = e - s;
    float bv = bias[f];
    float s1 = 0.f, s2 = 0.f;
    for (int n = s + j; n < e; n += NW) {
        float v = x[(long)n * F + f] + bv;
        s1 += v;
        s2 += v * v;
    }
    s1s[j][f] = s1;
    s2s[j][f] = s2;
    __syncthreads();
    if (j == 0) {
#pragma unroll
        for (int jj = 1; jj < NW; ++jj) { s1 += s1s[jj][f]; s2 += s2s[jj][f]; }
        float cnt = (float)max(count, 1);
        float mean = s1 / cnt;
        float mms = mean * ms[f];
        float var = s2 / cnt - 2.f * mms * mean + mms * mms;
        meanp[(long)g * F + f] = mean;
        istdp[(long)g * F + f] = 1.0f / sqrtf(var + EPS);
    }
}

// ---------- graph norm apply + residual + exact GELU (float4) ----------
template <int F>
__global__ void gn_apply_k(const float* __restrict__ x, const float* __restrict__ bias,
                           const int* __restrict__ batch, const float* __restrict__ meanp,
                           const float* __restrict__ istdp, const float* __restrict__ w,
                           const float* __restrict__ b, const float* __restrict__ ms,
                           const float* __restrict__ res, float* __restrict__ h, int N) {
    constexpr int F4 = F / 4;
    long i = (long)blockIdx.x * blockDim.x + threadIdx.x;
    if (i >= (long)N * F4) return;
    int n = (int)(i / F4), f4 = (int)(i % F4);
    int g = batch[n];
    long base = (long)n * F + f4 * 4;
    long gbase = (long)g * F + f4 * 4;
    float4 xv = *reinterpret_cast<const float4*>(&x[base]);
    float4 rv = *reinterpret_cast<const float4*>(&res[base]);
    float4 mv = *reinterpret_cast<const float4*>(&meanp[gbase]);
    float4 iv = *reinterpret_cast<const float4*>(&istdp[gbase]);
    float4 bv = *reinterpret_cast<const float4*>(&bias[f4 * 4]);
    float4 wv = *reinterpret_cast<const float4*>(&w[f4 * 4]);
    float4 bb = *reinterpret_cast<const float4*>(&b[f4 * 4]);
    float4 mw = *reinterpret_cast<const float4*>(&ms[f4 * 4]);
    float4 o;
    o.x = gelu_exact(wv.x * ((xv.x + bv.x) - mv.x * mw.x) * iv.x + bb.x + rv.x);
    o.y = gelu_exact(wv.y * ((xv.y + bv.y) - mv.y * mw.y) * iv.y + bb.y + rv.y);
    o.z = gelu_exact(wv.z * ((xv.z + bv.z) - mv.z * mw.z) * iv.z + bb.z + rv.z);
    o.w = gelu_exact(wv.w * ((xv.w + bv.w) - mv.w * mw.w) * iv.w + bb.w + rv.w);
    *reinterpret_cast<float4*>(&h[base]) = o;
}

// ---------- pooling + ego gate + MLP head ----------
__global__ void pool_head_k(const float* __restrict__ h2, const int* __restrict__ seg,
                            const float* __restrict__ Weg, const float* __restrict__ beg,
                            const float* __restrict__ Wf1, const float* __restrict__ bf1,
                            const float* __restrict__ Wf2, const float* __restrict__ bf2,
                            float* __restrict__ outp) {
    int g = blockIdx.x, t = threadIdx.x;
    int s = seg[g], epos = seg[g + 1];
    int count = epos - s;
    __shared__ float ssum[8][32];
    __shared__ float smax[8][32];
    __shared__ float xfinal[96];
    __shared__ float emb[32];
    int f = t % 32, j = t / 32;
    float sum = 0.f, mx = -INFINITY;
    for (int n = s + j; n < epos; n += 8) {
        float v = h2[(long)n * 32 + f];
        sum += v;
        mx = fmaxf(mx, v);
    }
    ssum[j][f] = sum;
    smax[j][f] = mx;
    __syncthreads();
    if (t < 32) {
        float acs = 0.f, acm = -INFINITY;
        for (int jj = 0; jj < 8; ++jj) { acs += ssum[jj][t]; acm = fmaxf(acm, smax[jj][t]); }
        float mean = acs / (float)max(count, 1);
        float mxv = (count > 0) ? acm : 0.0f;
        xfinal[t] = mean;
        smax[0][t] = mxv;
    }
    __syncthreads();
    if (t < 64) {
        float acc = beg[t];
        for (int k = 0; k < 32; ++k) acc += xfinal[k] * Weg[k * 64 + t];
        float gate = 1.0f / (1.0f + expf(-acc));
        float val = (t < 32) ? xfinal[t] : smax[0][t - 32];
        xfinal[32 + t] = gate * val;
    }
    __syncthreads();
    if (t < 32) {
        float acc = bf1[t];
        for (int k = 0; k < 96; ++k) acc += xfinal[k] * Wf1[k * 32 + t];
        emb[t] = gelu_exact(acc);
    }
    __syncthreads();
    if (t < 32) {
        float v = emb[t] * Wf2[t];
#pragma unroll
        for (int off = 16; off > 0; off >>= 1) v += __shfl_xor(v, off, 32);
        if (t == 0) outp[g] = v + bf2[0];
    }
}

// ---------- launcher ----------
extern "C" void kernel_launch(void* const* d_in, const int* in_sizes, int n_in, void* d_out,
                              int out_size, void* d_ws, size_t ws_size, hipStream_t stream) {
    const float* x      = (const float*)d_in[0];
    const int*   ei     = (const int*)d_in[1];
    const int*   batch  = (const int*)d_in[2];
    const float* Wl1    = (const float*)d_in[3];
    const float* bl1    = (const float*)d_in[4];
    const float* Wr1    = (const float*)d_in[5];
    const float* br1    = (const float*)d_in[6];
    const float* att1   = (const float*)d_in[7];
    const float* bias1  = (const float*)d_in[8];
    const float* gn1_w  = (const float*)d_in[9];
    const float* gn1_b  = (const float*)d_in[10];
    const float* gn1_ms = (const float*)d_in[11];
    const float* Wl2    = (const float*)d_in[12];
    const float* bl2    = (const float*)d_in[13];
    const float* Wr2    = (const float*)d_in[14];
    const float* br2    = (const float*)d_in[15];
    const float* att2   = (const float*)d_in[16];
    const float* bias2  = (const float*)d_in[17];
    const float* gn2_w  = (const float*)d_in[18];
    const float* gn2_b  = (const float*)d_in[19];
    const float* gn2_ms = (const float*)d_in[20];
    const float* Wp1    = (const float*)d_in[21];
    const float* bp1    = (const float*)d_in[22];
    const float* Wp2    = (const float*)d_in[23];
    const float* bp2    = (const float*)d_in[24];
    const float* Weg    = (const float*)d_in[25];
    const float* beg    = (const float*)d_in[26];
    const float* Wf1    = (const float*)d_in[27];
    const float* bf1    = (const float*)d_in[28];
    const float* Wf2    = (const float*)d_in[29];
    const float* bf2    = (const float*)d_in[30];
    float* outp = (float*)d_out;

    const int N = in_sizes[2];
    const int E = in_sizes[1] / 2;
    const int Etot = E + N;
    const int G = out_size;
    constexpr int HC = 128, C = 32;

    char* ws = (char*)d_ws;
    size_t off = 0;
    auto alloc = [&](size_t bytes) -> void* {
        void* p = ws + off;
        off += (bytes + 255) & ~(size_t)255;
        return p;
    };
    int*   seg    = (int*)alloc((size_t)(G + 1) * 4);
    int*   cnt    = (int*)alloc((size_t)N * 4);
    int*   cur    = (int*)alloc((size_t)N * 4);
    int*   rowptr = (int*)alloc((size_t)(N + 1) * 4);
    int*   esrc   = (int*)alloc((size_t)Etot * 4);
    float* xl1    = (float*)alloc((size_t)N * HC * 4);
    float* xr1    = (float*)alloc((size_t)N * HC * 4);
    float* res1   = (float*)alloc((size_t)N * HC * 4);
    float* out1   = (float*)alloc((size_t)N * HC * 4);
    float* mean1  = (float*)alloc((size_t)G * HC * 4);
    float* istd1  = (float*)alloc((size_t)G * HC * 4);
    float* xl2    = (float*)alloc((size_t)N * C * 4);
    float* xr2    = (float*)alloc((size_t)N * C * 4);
    float* res2   = (float*)alloc((size_t)N * C * 4);
    float* out2   = (float*)alloc((size_t)N * C * 4);
    float* h2     = (float*)alloc((size_t)N * C * 4);
    float* mean2  = (float*)alloc((size_t)G * C * 4);
    float* istd2  = (float*)alloc((size_t)G * C * 4);
    float* h1     = xl1;  // alias: xl1 dead after gat1_k
    (void)ws_size; (void)n_in;

    // init + CSR build
    seg_bounds_k<<<(N + 255) / 256, 256, 0, stream>>>(batch, N, G, seg);
    hipMemsetAsync(cnt, 0, (size_t)N * 4, stream);
    hipMemsetAsync(cur, 0, (size_t)N * 4, stream);
    hist_k<<<(Etot + 255) / 256, 256, 0, stream>>>(ei, E, Etot, cnt);
    scan_k<<<1, 1024, 0, stream>>>(cnt, N, rowptr);
    scatter_k<<<(Etot + 255) / 256, 256, 0, stream>>>(ei, E, Etot, rowptr, cur, esrc);

    // ---- layer 1 ----
    // 512 threads, BM = 16*4 = 64 rows x 128 cols; LDS 56 KB
    linear3v2_k<128, 32, 16, 4><<<(N + 63) / 64, 512, 0, stream>>>(
        x, Wl1, bl1, Wr1, br1, Wp1, bp1, xl1, xr1, res1, N);
    gat1_k<<<(N + 1) / 2, 256, 0, stream>>>(xl1, xr1, att1, rowptr, esrc, out1, N);
    gn_stats_k<128, 4><<<G, 512, 0, stream>>>(out1, bias1, gn1_ms, seg, mean1, istd1);
    gn_apply_k<128><<<(int)(((long)N * 32 + 255) / 256), 256, 0, stream>>>(
        out1, bias1, batch, mean1, istd1, gn1_w, gn1_b, gn1_ms, res1, h1, N);

    // ---- layer 2 ----
    // 256 threads, BM = 32*4 = 128 rows x 32 cols; LDS 28 KB
    linear3v2_k<32, 8, 32, 4><<<(N + 127) / 128, 256, 0, stream>>>(
        h1, Wl2, bl2, Wr2, br2, Wp2, bp2, xl2, xr2, res2, N);
    gat2_k<<<(N + 7) / 8, 256, 0, stream>>>(xl2, xr2, att2, rowptr, esrc, out2, N);
    gn_stats_k<32, 16><<<G, 512, 0, stream>>>(out2, bias2, gn2_ms, seg, mean2, istd2);
    gn_apply_k<32><<<(int)(((long)N * 8 + 255) / 256), 256, 0, stream>>>(
        out2, bias2, batch, mean2, istd2, gn2_w, gn2_b, gn2_ms, res2, h2, N);

    // ---- pooling + gate + head ----
    pool_head_k<<<G, 256, 0, stream>>>(h2, seg, Weg, beg, Wf1, bf1, Wf2, bf2, outp);
}